// Round 14
// baseline (199.450 us; speedup 1.0000x reference)
//
#include <hip/hip_runtime.h>
#include <hip/hip_bf16.h>

#define HH 32
#define KVHN 8
#define HD 64
#define DMODEL 2048
#define SEQ 2048
#define BB 2
#define NTOK 4096     // BB*SEQ
#define DKV 512       // KVHN*HD
#define NQKV 3072     // DMODEL + 2*DKV

typedef __bf16 bf16x8 __attribute__((ext_vector_type(8)));
typedef __bf16 bf16x4 __attribute__((ext_vector_type(4)));
typedef float  f32x4  __attribute__((ext_vector_type(4)));

typedef const __attribute__((address_space(1))) void gvoid_t;
typedef __attribute__((address_space(3))) void lvoid_t;

__device__ inline void glds16(const void* g, void* l) {
  __builtin_amdgcn_global_load_lds((gvoid_t*)g, (lvoid_t*)l, 16, 0, 0);
}

__device__ inline f32x4 mfma16(bf16x8 a, bf16x8 b, f32x4 c) {
  return __builtin_amdgcn_mfma_f32_16x16x32_bf16(a, b, c, 0, 0, 0);
}

// 2^x via v_exp_f32 (glibc shadows __exp2f; this is the HW op directly)
__device__ inline float fast_exp2(float x) {
  float r;
  asm("v_exp_f32 %0, %1" : "=v"(r) : "v"(x));
  return r;
}

// ---------------- merged prep kernel ----------------
// One launch, 18432 blocks of 256 threads, blockIdx-range dispatch:
//   [0, 8192)      hidden f32 -> bf16 (elementwise, 4/thread)
//   [8192, 12288)  wq transpose  -> WT[0..2048)
//   [12288, 14336) wk/wv transpose -> WT[2048..3072)
//   [14336, 18432) wo transpose  -> WoT

__global__ __launch_bounds__(256)
void k_prep(const float* __restrict__ hidden, __bf16* __restrict__ Abf,
            const float* __restrict__ wq, const float* __restrict__ wk,
            const float* __restrict__ wv, const float* __restrict__ wo,
            __bf16* __restrict__ WT, __bf16* __restrict__ WoT) {
  __shared__ float tile[32][33];
  const int id = blockIdx.x, tid = threadIdx.x;
  if (id < 8192) {
    int i = (id * 256 + tid) * 4;
    f32x4 v = *(const f32x4*)(hidden + i);
    bf16x4 o;
    o[0] = (__bf16)v[0]; o[1] = (__bf16)v[1];
    o[2] = (__bf16)v[2]; o[3] = (__bf16)v[3];
    *(bf16x4*)(Abf + i) = o;
    return;
  }
  const float* W; __bf16* T; int K, N, n0, k0;
  if (id < 12288) {           // wq
    int t = id - 8192; W = wq; T = WT; K = 2048; N = 2048;
    n0 = (t & 63) * 32; k0 = (t >> 6) * 32;
  } else if (id < 14336) {    // wk (z=0) / wv (z=1)
    int t = id - 12288; int z = t >> 10;
    W = z ? wv : wk; T = WT + (size_t)(2048 + z * 512) * 2048;
    K = 2048; N = 512;
    n0 = (t & 15) * 32; k0 = ((t >> 4) & 63) * 32;
  } else {                    // wo
    int t = id - 14336; W = wo; T = WoT; K = 2048; N = 2048;
    n0 = (t & 63) * 32; k0 = (t >> 6) * 32;
  }
  int tx = tid & 31, ty = tid >> 5;
#pragma unroll
  for (int i = 0; i < 32; i += 8)
    tile[ty + i][tx] = W[(size_t)(k0 + ty + i) * N + n0 + tx];
  __syncthreads();
#pragma unroll
  for (int i = 0; i < 32; i += 8)
    T[(size_t)(n0 + ty + i) * K + k0 + tx] = (__bf16)tile[tx][ty + i];
}

// ---------------- 2-phase GEMM (WO): C = A * BT^T ----------------
// 128x128 tile, BK=32, 4 waves, 32KB LDS, row-pair XOR-8 LDS layout
// (0 bank conflicts measured, round 10), counted-vmcnt prefetch.

__device__ inline void stc(float* p, float v)  { *p = v; }
__device__ inline void stc(__bf16* p, float v) { *p = (__bf16)v; }

template <int EPI, typename CT>
__global__ __launch_bounds__(256, 4)
void k_gemm3(const __bf16* __restrict__ A, const __bf16* __restrict__ BT,
             CT* __restrict__ C, int M, int N, int K) {
  __shared__ alignas(16) __bf16 Al[2][128 * 32];
  __shared__ alignas(16) __bf16 Bl[2][128 * 32];
  const int tid = threadIdx.x;
  const int wid = tid >> 6, lane = tid & 63, g = lane >> 4, r16 = lane & 15;
  const int wm = wid >> 1, wn = wid & 1;
  const int nbm = M >> 7, nbn = N >> 7;
  const int nwg = nbm * nbn;
  int id = blockIdx.x;
  id = (id & 7) * (nwg >> 3) + (id >> 3);   // XCD swizzle (nwg % 8 == 0 here)
  const int bm = id % nbm, bn = id / nbm;

  const int pp = tid >> 3;
  const int c8 = (tid & 7) ^ (pp & 7);
  const int sr1 = 2 * pp + (c8 >> 2);
  const int sr2 = 64 + sr1;
  const int c1 = (c8 & 3) * 8;
  const __bf16* gA1 = A + (size_t)(bm * 128 + sr1) * K + c1;
  const __bf16* gA2 = A + (size_t)(bm * 128 + sr2) * K + c1;
  const __bf16* gB1 = BT + (size_t)(bn * 128 + sr1) * K + c1;
  const __bf16* gB2 = BT + (size_t)(bn * 128 + sr2) * K + c1;

  int aoff[4], boff[4];
#pragma unroll
  for (int m = 0; m < 4; ++m) {
    int row = wm * 64 + m * 16 + r16;
    aoff[m] = (row >> 1) * 64 + (((((row & 1) << 2) | g) ^ ((row >> 1) & 7)) * 8);
  }
#pragma unroll
  for (int n = 0; n < 4; ++n) {
    int row = wn * 64 + n * 16 + r16;
    boff[n] = (row >> 1) * 64 + (((((row & 1) << 2) | g) ^ ((row >> 1) & 7)) * 8);
  }

  auto STAGE = [&](int sl, int kt) {
    const int ko = kt * 32;
    glds16(gA1 + ko, &Al[sl][tid * 8]);
    glds16(gA2 + ko, &Al[sl][2048 + tid * 8]);
    glds16(gB1 + ko, &Bl[sl][tid * 8]);
    glds16(gB2 + ko, &Bl[sl][2048 + tid * 8]);
  };

  f32x4 acc[4][4] = {};
  const int nk = K >> 5;

  STAGE(0, 0);
  for (int kt = 0; kt < nk; ++kt) {
    const int s = kt & 1;
    if (kt + 1 < nk) {
      STAGE(s ^ 1, kt + 1);
      asm volatile("s_waitcnt vmcnt(4)" ::: "memory");
    } else {
      asm volatile("s_waitcnt vmcnt(0)" ::: "memory");
    }
    __builtin_amdgcn_s_barrier();
    bf16x8 af[4], bfr[4];
#pragma unroll
    for (int m = 0; m < 4; ++m) af[m] = *(const bf16x8*)&Al[s][aoff[m]];
#pragma unroll
    for (int n = 0; n < 4; ++n) bfr[n] = *(const bf16x8*)&Bl[s][boff[n]];
    __builtin_amdgcn_s_setprio(1);
#pragma unroll
    for (int m = 0; m < 4; ++m)
#pragma unroll
      for (int n = 0; n < 4; ++n)
        acc[m][n] = mfma16(af[m], bfr[n], acc[m][n]);
    __builtin_amdgcn_s_setprio(0);
    __builtin_amdgcn_s_barrier();
  }

#pragma unroll
  for (int m = 0; m < 4; ++m) {
    int row = bm * 128 + wm * 64 + m * 16 + g * 4;
#pragma unroll
    for (int n = 0; n < 4; ++n) {
      int col = bn * 128 + wn * 64 + n * 16 + r16;
#pragma unroll
      for (int r = 0; r < 4; ++r)
        stc(&C[(size_t)(row + r) * N + col], acc[m][n][r]);
    }
  }
}

// ---------------- QKV GEMM: 128x256 block, 64x128 wave-tile ----------------
// Motivation (round-13 counters): QKV@3blk/CU and WO@2blk/CU run at the SAME
// per-CU block-iter rate (2.67 vs 2.72 /us) -> a shared per-CU pipe (LDS
// read) saturates at 2 blocks.  64x64 wave-tiles cost 8 b128 / 4096 outputs;
// 64x128 tiles cost 12 b128 / 8192 outputs = 25% less pipe per output and
// 2x output per block-iter.  Same 2-phase schedule, same row-pair XOR-8
// swizzle (0 conflicts), BK=32, 4 waves, LDS 48KB (A 2x8KB + B 2x16KB).
// Grid 32x12 = 384 blocks (1.5/CU; the 2-resident CUs are the saturating
// config).  Each wave's 128 cols = exactly 2 heads (all Q/K/V region
// boundaries are 128-aligned): epilogue loops h2 in {0,1}, RMSNorm per
// head-group of 4 n-frags, RoPE n^2 pairing stays intra-head.

__global__ __launch_bounds__(256, 2)
void k_gemmQ(const __bf16* __restrict__ A, const __bf16* __restrict__ BT,
             const float* __restrict__ cosT, const float* __restrict__ sinT,
             const float* __restrict__ qw, const float* __restrict__ kw,
             __bf16* __restrict__ Qr, __bf16* __restrict__ Kr,
             __bf16* __restrict__ Vt) {
  const int K = DMODEL;
  __shared__ alignas(16) __bf16 Al[2][128 * 32];
  __shared__ alignas(16) __bf16 Bl[2][256 * 32];
  const int tid = threadIdx.x;
  const int wid = tid >> 6, lane = tid & 63, g = lane >> 4, r16 = lane & 15;
  const int wm = wid >> 1, wn = wid & 1;
  const int nbm = 32, nwg = 384;                 // 4096/128 x 3072/256
  int id = blockIdx.x;
  id = (id & 7) * (nwg >> 3) + (id >> 3);        // XCD swizzle (384 % 8 == 0)
  const int bm = id % nbm, bn = id / nbm;

  // staging source: inverse of the row-pair XOR-8 swizzle
  const int pp = tid >> 3;
  const int c8 = (tid & 7) ^ (pp & 7);
  const int sr1 = 2 * pp + (c8 >> 2);            // 0..63
  const int c1 = (c8 & 3) * 8;
  const __bf16* gA1 = A + (size_t)(bm * 128 + sr1) * K + c1;
  const __bf16* gA2 = A + (size_t)(bm * 128 + 64 + sr1) * K + c1;
  const __bf16* gB0 = BT + (size_t)(bn * 256 + sr1) * K + c1;  // +64k*K per group

  // fragment read offsets (row-pair swizzle; B rows 0..255)
  int aoff[4], boff[8];
#pragma unroll
  for (int m = 0; m < 4; ++m) {
    int row = wm * 64 + m * 16 + r16;
    aoff[m] = (row >> 1) * 64 + (((((row & 1) << 2) | g) ^ ((row >> 1) & 7)) * 8);
  }
#pragma unroll
  for (int n = 0; n < 8; ++n) {
    int row = wn * 128 + n * 16 + r16;
    boff[n] = (row >> 1) * 64 + (((((row & 1) << 2) | g) ^ ((row >> 1) & 7)) * 8);
  }

  auto STAGE = [&](int sl, int kt) {             // 6 glds / thread
    const int ko = kt * 32;
    glds16(gA1 + ko, &Al[sl][tid * 8]);
    glds16(gA2 + ko, &Al[sl][2048 + tid * 8]);
    glds16(gB0 + ko,                    &Bl[sl][tid * 8]);
    glds16(gB0 + (size_t)64 * K + ko,   &Bl[sl][2048 + tid * 8]);
    glds16(gB0 + (size_t)128 * K + ko,  &Bl[sl][4096 + tid * 8]);
    glds16(gB0 + (size_t)192 * K + ko,  &Bl[sl][6144 + tid * 8]);
  };

  f32x4 acc[4][8] = {};
  const int nk = K >> 5;                          // 64

  STAGE(0, 0);
  for (int kt = 0; kt < nk; ++kt) {
    const int s = kt & 1;
    if (kt + 1 < nk) {
      STAGE(s ^ 1, kt + 1);
      asm volatile("s_waitcnt vmcnt(6)" ::: "memory");
    } else {
      asm volatile("s_waitcnt vmcnt(0)" ::: "memory");
    }
    __builtin_amdgcn_s_barrier();
    bf16x8 af[4], bfr[8];
#pragma unroll
    for (int m = 0; m < 4; ++m) af[m] = *(const bf16x8*)&Al[s][aoff[m]];
#pragma unroll
    for (int n = 0; n < 8; ++n) bfr[n] = *(const bf16x8*)&Bl[s][boff[n]];
    __builtin_amdgcn_s_setprio(1);
#pragma unroll
    for (int m = 0; m < 4; ++m)
#pragma unroll
      for (int n = 0; n < 8; ++n)
        acc[m][n] = mfma16(af[m], bfr[n], acc[m][n]);
    __builtin_amdgcn_s_setprio(0);
    __builtin_amdgcn_s_barrier();   // guard: all reads of slot s done before overwrite
  }

  // fused QKV epilogue: wave covers 2 heads (h2 = 0,1), 4 n-frags each
  const float QSCALE = 0.18033688011112042f;     // 0.125 * log2(e)
#pragma unroll
  for (int h2 = 0; h2 < 2; ++h2) {
    const int cb = bn * 256 + wn * 128 + h2 * 64;
    const int nb0 = h2 * 4;
    if (cb < DMODEL + DKV) {
      const bool isq = cb < DMODEL;
      const float* wp = isq ? qw : kw;
      const float qs = isq ? QSCALE : 1.0f;
      float w4[4];
#pragma unroll
      for (int n = 0; n < 4; ++n) w4[n] = wp[n * 16 + r16];
#pragma unroll
      for (int m = 0; m < 4; ++m) {
        const int rowm = bm * 128 + wm * 64 + m * 16 + g * 4;
        float ss[4];
#pragma unroll
        for (int r = 0; r < 4; ++r) {
          ss[r] = acc[m][nb0 + 0][r] * acc[m][nb0 + 0][r] +
                  acc[m][nb0 + 1][r] * acc[m][nb0 + 1][r] +
                  acc[m][nb0 + 2][r] * acc[m][nb0 + 2][r] +
                  acc[m][nb0 + 3][r] * acc[m][nb0 + 3][r];
#pragma unroll
          for (int mk = 1; mk < 16; mk <<= 1) ss[r] += __shfl_xor(ss[r], mk);
          ss[r] = rsqrtf(ss[r] * (1.0f / HD) + 1e-6f);
        }
#pragma unroll
        for (int r = 0; r < 4; ++r) {
          const int t = rowm + r;
          const int sidx = t & (SEQ - 1);
          const float inv_ = ss[r];
#pragma unroll
          for (int n = 0; n < 4; ++n) {
            const int d = n * 16 + r16;
            const float xn = acc[m][nb0 + n][r] * inv_ * w4[n];
            const float xp = acc[m][nb0 + (n ^ 2)][r] * inv_ * w4[n ^ 2];
            const float rot = (n < 2) ? -xp : xp;
            const float cv = cosT[sidx * HD + d], sv = sinT[sidx * HD + d];
            const float o = (xn * cv + rot * sv) * qs;
            if (isq) {
              const int hq = cb >> 6;
              Qr[((size_t)t * HH + hq) * HD + d] = (__bf16)o;
            } else {
              const int kvh = (cb - DMODEL) >> 6;
              Kr[((size_t)t * KVHN + kvh) * HD + d] = (__bf16)o;
            }
          }
        }
      }
    } else {
      // V: write directly TRANSPOSED into VT[b][c][s]
      const int vc0 = cb - (DMODEL + DKV);
#pragma unroll
      for (int m = 0; m < 4; ++m) {
        const int rowm = bm * 128 + wm * 64 + m * 16 + g * 4;
        const int bb2 = rowm >> 11;              // batch (SEQ = 2048)
        const int s0 = rowm & (SEQ - 1);
#pragma unroll
        for (int n = 0; n < 4; ++n) {
          const int c = vc0 + n * 16 + r16;
          bf16x4 pk;
#pragma unroll
          for (int r = 0; r < 4; ++r) pk[r] = (__bf16)acc[m][nb0 + n][r];
          *(bf16x4*)&Vt[((size_t)bb2 * DKV + c) * SEQ + s0] = pk;
        }
      }
    }
  }
}

// ---------------- flash attention (causal, GQA) ----------------
// R6/R11-proven geometry (best measured): grid flat 512, block 512 (8 waves
// x 16 q-rows; 16 waves/CU at 2 blocks/CU).  EQUAL-WORK BLOCKS: sequential
// complementary pair {15-j, j} (j = f&7) of 128-row q-tiles -> 34
// kv-iterations/block.  SWAPPED QK^T: sacc = mfma(kf, qf) gives S^T; P
// store is 4x ds_write_b64 into row-major P[q][kv]; PV b128 read unchanged.
// (Round 13 showed 3-deep counted-vmcnt is neutral at 2 blk/CU -> keep the
// simpler 2-deep form.)

__global__ __launch_bounds__(512)
void k_attn(const __bf16* __restrict__ Q, const __bf16* __restrict__ Kg,
            const __bf16* __restrict__ VT, __bf16* __restrict__ O) {
  __shared__ alignas(16) __bf16 Kl[2][64 * 64];
  __shared__ alignas(16) __bf16 Vl[2][64 * 64];
  __shared__ alignas(16) __bf16 Pl[8][16 * 72];
  const int f = blockIdx.x;
  const int b = f >> 8;
  const int h = (f & 255) >> 3;
  const int j = f & 7;
  const int kvh = h >> 2;
  const int tid = threadIdx.x, wid = tid >> 6, lane = tid & 63;
  const int g = lane >> 4, r16 = lane & 15;
  __bf16* Pw = Pl[wid];

  const int rr = lane >> 3;                 // row within wave's 8-row slab
  const int cc = (lane & 7) ^ rr;           // swizzled source chunk

  auto STAGE = [&](int buf, int kb) {
    const int krow = kb * 64 + wid * 8 + rr;
    glds16(&Kg[((size_t)(b * SEQ + krow) * KVHN + kvh) * HD + cc * 8],
           &Kl[buf][wid * 512]);
    const int d = wid * 8 + rr;
    glds16(&VT[(size_t)(b * DKV + kvh * HD + d) * SEQ + (size_t)kb * 64 + cc * 8],
           &Vl[buf][wid * 512]);
  };

#pragma unroll 1
  for (int phase = 0; phase < 2; ++phase) {
    const int qt = phase ? j : 15 - j;      // heavy tile first
    const int q0 = qt * 128 + wid * 16;
    const int ntile = 2 * qt + 2;

    bf16x8 qf[2];
#pragma unroll
    for (int h2 = 0; h2 < 2; ++h2)
      qf[h2] = *(const bf16x8*)&Q[(((size_t)b * SEQ + q0 + r16) * HH + h) * HD + h2 * 32 + g * 8];

    f32x4 acc[4] = {};
    float l_q = 0.0f;   // per-lane partial denominator for q = q0 + r16

    STAGE(0, 0);
    asm volatile("s_waitcnt vmcnt(0)" ::: "memory");
    __syncthreads();

    for (int kb = 0; kb < ntile; ++kb) {
      const int cur = kb & 1;
      if (kb + 1 < ntile) STAGE(cur ^ 1, kb + 1);   // prefetch next tile
      const __bf16* Kb = Kl[cur];
      const __bf16* Vb = Vl[cur];
      if (kb * 64 <= q0 + 15) {                     // tile intersects rows
        bf16x8 kf[4][2];
#pragma unroll
        for (int ks = 0; ks < 4; ++ks)
#pragma unroll
          for (int h2 = 0; h2 < 2; ++h2) {
            const int p = r16 + ks * 16;
            const int ch = (g + 4 * h2) ^ (p & 7);
            kf[ks][h2] = *(const bf16x8*)&Kb[p * 64 + ch * 8];
          }
        const bool needmask = (kb * 64 + 63 > q0); // only diagonal tiles mask
        float svv[4][4];
        __builtin_amdgcn_s_setprio(1);
#pragma unroll
        for (int ks = 0; ks < 4; ++ks) {
          f32x4 sacc = {-12.f, -12.f, -12.f, -12.f};   // fixed max in C-init
          sacc = mfma16(kf[ks][0], qf[0], sacc);       // SWAPPED: S^T
          sacc = mfma16(kf[ks][1], qf[1], sacc);
#pragma unroll
          for (int r = 0; r < 4; ++r) svv[ks][r] = sacc[r];
        }
        __builtin_amdgcn_s_setprio(0);
        if (needmask) {
#pragma unroll
          for (int ks = 0; ks < 4; ++ks)
#pragma unroll
            for (int r = 0; r < 4; ++r) {
              int pg = kb * 64 + ks * 16 + g * 4 + r;  // kv (swapped)
              int qg = q0 + r16;                       // q  (swapped)
              if (pg > qg) svv[ks][r] = -1e30f;
            }
        }
        // exp2 + packed b64 store into P[q=r16][kv]: contiguous 4 per ks
#pragma unroll
        for (int ks = 0; ks < 4; ++ks) {
          bf16x4 pk;
#pragma unroll
          for (int r = 0; r < 4; ++r) {
            float p = fast_exp2(svv[ks][r]);
            l_q += p;
            pk[r] = (__bf16)p;
          }
          *(bf16x4*)&Pw[r16 * 72 + ks * 16 + g * 4] = pk;
        }
        bf16x8 pf0 = *(const bf16x8*)&Pw[r16 * 72 + g * 8];
        bf16x8 pf1 = *(const bf16x8*)&Pw[r16 * 72 + 32 + g * 8];
        __builtin_amdgcn_s_setprio(1);
#pragma unroll
        for (int nb = 0; nb < 4; ++nb) {
          const int d = r16 + nb * 16;
          const int ch0 = g ^ (d & 7), ch1 = (4 + g) ^ (d & 7);
          bf16x8 vf0 = *(const bf16x8*)&Vb[d * 64 + ch0 * 8];
          bf16x8 vf1 = *(const bf16x8*)&Vb[d * 64 + ch1 * 8];
          acc[nb] = mfma16(pf0, vf0, acc[nb]);
          acc[nb] = mfma16(pf1, vf1, acc[nb]);
        }
        __builtin_amdgcn_s_setprio(0);
      }
      asm volatile("s_waitcnt vmcnt(0)" ::: "memory");
      __syncthreads();
    }
    // epilogue: complete l over kv (sum the 4 g-groups), redistribute, store
    l_q += __shfl_xor(l_q, 16);
    l_q += __shfl_xor(l_q, 32);
    const float invq = 1.0f / l_q;
    float inv[4];
#pragma unroll
    for (int r = 0; r < 4; ++r) inv[r] = __shfl(invq, g * 4 + r);
#pragma unroll
    for (int nb = 0; nb < 4; ++nb)
#pragma unroll
      for (int r = 0; r < 4; ++r)
        O[(((size_t)b * SEQ + q0 + g * 4 + r) * HH + h) * HD + nb * 16 + r16] =
            (__bf16)(acc[nb][r] * inv[r]);
  }
}

// ---------------- launch ----------------

extern "C" void kernel_launch(void* const* d_in, const int* in_sizes, int n_in,
                              void* d_out, int out_size, void* d_ws, size_t ws_size,
                              hipStream_t stream) {
  const float* hidden = (const float*)d_in[0];
  const float* cosT   = (const float*)d_in[1];
  const float* sinT   = (const float*)d_in[2];
  const float* wq     = (const float*)d_in[3];
  const float* wk     = (const float*)d_in[4];
  const float* wv     = (const float*)d_in[5];
  const float* wo     = (const float*)d_in[6];
  const float* qw     = (const float*)d_in[7];
  const float* kw     = (const float*)d_in[8];
  float* out = (float*)d_out;
  char* ws = (char*)d_ws;

  // workspace layout (64 MB, lifetime-aliased):
  __bf16* Abf  = (__bf16*)(ws);                      // [0,16M) hidden bf16; later Ob
  __bf16* Ob   = Abf;
  __bf16* WT   = (__bf16*)(ws + (16u << 20));        // [16,28M) qkv weights^T
  __bf16* Qr   = (__bf16*)(ws + (28u << 20));        // [28,44M) Q roped (log2 domain)
  __bf16* Kr   = (__bf16*)(ws + (44u << 20));        // [44,48M) K roped
  __bf16* VT   = (__bf16*)(ws + (52u << 20));        // [52,56M) V transposed (direct)
  __bf16* WoT  = (__bf16*)(ws + (56u << 20));        // [56,64M)

  k_prep<<<18432, 256, 0, stream>>>(hidden, Abf, wq, wk, wv, wo, WT, WoT);

  // QKV: 128x256 blocks -> 32 x 12 = 384 blocks
  k_gemmQ<<<384, 256, 0, stream>>>(Abf, WT, cosT, sinT, qw, kw, Qr, Kr, VT);

  k_attn<<<dim3(512), 512, 0, stream>>>(Qr, Kr, VT, Ob);

  k_gemm3<0, float><<<512, 256, 0, stream>>>(Ob, WoT, out,
      NTOK, DMODEL, DMODEL);
}

// Round 15
// 186.372 us; speedup vs baseline: 1.0702x; 1.0702x over previous
//
#include <hip/hip_runtime.h>
#include <hip/hip_bf16.h>

#define HH 32
#define KVHN 8
#define HD 64
#define DMODEL 2048
#define SEQ 2048
#define BB 2
#define NTOK 4096     // BB*SEQ
#define DKV 512       // KVHN*HD
#define NQKV 3072     // DMODEL + 2*DKV

typedef __bf16 bf16x8 __attribute__((ext_vector_type(8)));
typedef __bf16 bf16x4 __attribute__((ext_vector_type(4)));
typedef float  f32x4  __attribute__((ext_vector_type(4)));

typedef const __attribute__((address_space(1))) void gvoid_t;
typedef __attribute__((address_space(3))) void lvoid_t;

__device__ inline void glds16(const void* g, void* l) {
  __builtin_amdgcn_global_load_lds((gvoid_t*)g, (lvoid_t*)l, 16, 0, 0);
}

__device__ inline f32x4 mfma16(bf16x8 a, bf16x8 b, f32x4 c) {
  return __builtin_amdgcn_mfma_f32_16x16x32_bf16(a, b, c, 0, 0, 0);
}

// 2^x via v_exp_f32 (glibc shadows __exp2f; this is the HW op directly)
__device__ inline float fast_exp2(float x) {
  float r;
  asm("v_exp_f32 %0, %1" : "=v"(r) : "v"(x));
  return r;
}

// ---------------- merged prep kernel ----------------
// One launch, 18432 blocks of 256 threads, blockIdx-range dispatch:
//   [0, 8192)      hidden f32 -> bf16 (elementwise, 4/thread)
//   [8192, 12288)  wq transpose  -> WT[0..2048)
//   [12288, 14336) wk/wv transpose -> WT[2048..3072)
//   [14336, 18432) wo transpose  -> WoT
// HBM-bound (~13 us for ~108 MB of traffic).

__global__ __launch_bounds__(256)
void k_prep(const float* __restrict__ hidden, __bf16* __restrict__ Abf,
            const float* __restrict__ wq, const float* __restrict__ wk,
            const float* __restrict__ wv, const float* __restrict__ wo,
            __bf16* __restrict__ WT, __bf16* __restrict__ WoT) {
  __shared__ float tile[32][33];
  const int id = blockIdx.x, tid = threadIdx.x;
  if (id < 8192) {
    int i = (id * 256 + tid) * 4;
    f32x4 v = *(const f32x4*)(hidden + i);
    bf16x4 o;
    o[0] = (__bf16)v[0]; o[1] = (__bf16)v[1];
    o[2] = (__bf16)v[2]; o[3] = (__bf16)v[3];
    *(bf16x4*)(Abf + i) = o;
    return;
  }
  const float* W; __bf16* T; int K, N, n0, k0;
  if (id < 12288) {           // wq
    int t = id - 8192; W = wq; T = WT; K = 2048; N = 2048;
    n0 = (t & 63) * 32; k0 = (t >> 6) * 32;
  } else if (id < 14336) {    // wk (z=0) / wv (z=1)
    int t = id - 12288; int z = t >> 10;
    W = z ? wv : wk; T = WT + (size_t)(2048 + z * 512) * 2048;
    K = 2048; N = 512;
    n0 = (t & 15) * 32; k0 = ((t >> 4) & 63) * 32;
  } else {                    // wo
    int t = id - 14336; W = wo; T = WoT; K = 2048; N = 2048;
    n0 = (t & 63) * 32; k0 = (t >> 6) * 32;
  }
  int tx = tid & 31, ty = tid >> 5;
#pragma unroll
  for (int i = 0; i < 32; i += 8)
    tile[ty + i][tx] = W[(size_t)(k0 + ty + i) * N + n0 + tx];
  __syncthreads();
#pragma unroll
  for (int i = 0; i < 32; i += 8)
    T[(size_t)(n0 + ty + i) * K + k0 + tx] = (__bf16)tile[tx][ty + i];
}

// ---------------- pipelined GEMM: C = A[M][K] * BT[N][K]^T ----------------
// 128x128 tile, BK=32, 4 waves (2M x 2N, 64x64 each), 256 thr, 32KB LDS.
// MEASURED-BEST configuration (round 11, 186.0 us total):
//  - counted-vmcnt prefetch (vmcnt(4), never 0 mid-loop), setprio MFMA
//  - row-pair XOR-8 LDS layout: 0 bank conflicts measured (round 10)
//  - >= 2 blocks/CU residency is ESSENTIAL (rounds 7/9/14: exposing the
//    barrier drain at 1-1.5 blocks/CU regresses 15-25%)
//  - 8-phase 256^2 (rounds 4/12) and 128x256 tiles (round 14) both lose
//    on this problem's shapes.  Closed avenues.
// EPI==0: plain store to C.  EPI==1: fused QKV epilogue (per-head RMSNorm +
// RoPE, Q pre-scaled by 0.125*log2(e)); V written DIRECTLY TRANSPOSED into
// VT[b][c][s].

__device__ inline void stc(float* p, float v)  { *p = v; }
__device__ inline void stc(__bf16* p, float v) { *p = (__bf16)v; }

template <int EPI, typename CT>
__global__ __launch_bounds__(256, 4)
void k_gemm3(const __bf16* __restrict__ A, const __bf16* __restrict__ BT,
             CT* __restrict__ C, int M, int N, int K,
             const float* __restrict__ cosT, const float* __restrict__ sinT,
             const float* __restrict__ qw, const float* __restrict__ kw,
             __bf16* __restrict__ Qr, __bf16* __restrict__ Kr,
             __bf16* __restrict__ Vt) {
  __shared__ alignas(16) __bf16 Al[2][128 * 32];
  __shared__ alignas(16) __bf16 Bl[2][128 * 32];
  const int tid = threadIdx.x;
  const int wid = tid >> 6, lane = tid & 63, g = lane >> 4, r16 = lane & 15;
  const int wm = wid >> 1, wn = wid & 1;
  const int nbm = M >> 7, nbn = N >> 7;
  const int nwg = nbm * nbn;
  int id = blockIdx.x;
  id = (id & 7) * (nwg >> 3) + (id >> 3);   // XCD swizzle (nwg % 8 == 0 here)
  const int bm = id % nbm, bn = id / nbm;

  // staging source: inverse of the row-pair XOR-8 swizzle
  const int pp = tid >> 3;                  // line index 0..31 (rows 0..63)
  const int c8 = (tid & 7) ^ (pp & 7);
  const int sr1 = 2 * pp + (c8 >> 2);       // 0..63
  const int sr2 = 64 + sr1;                 // 64..127
  const int c1 = (c8 & 3) * 8;
  const __bf16* gA1 = A + (size_t)(bm * 128 + sr1) * K + c1;
  const __bf16* gA2 = A + (size_t)(bm * 128 + sr2) * K + c1;
  const __bf16* gB1 = BT + (size_t)(bn * 128 + sr1) * K + c1;
  const __bf16* gB2 = BT + (size_t)(bn * 128 + sr2) * K + c1;

  // fragment read offsets (row-pair swizzle)
  int aoff[4], boff[4];
#pragma unroll
  for (int m = 0; m < 4; ++m) {
    int row = wm * 64 + m * 16 + r16;
    aoff[m] = (row >> 1) * 64 + (((((row & 1) << 2) | g) ^ ((row >> 1) & 7)) * 8);
  }
#pragma unroll
  for (int n = 0; n < 4; ++n) {
    int row = wn * 64 + n * 16 + r16;
    boff[n] = (row >> 1) * 64 + (((((row & 1) << 2) | g) ^ ((row >> 1) & 7)) * 8);
  }

  auto STAGE = [&](int sl, int kt) {
    const int ko = kt * 32;
    glds16(gA1 + ko, &Al[sl][tid * 8]);
    glds16(gA2 + ko, &Al[sl][2048 + tid * 8]);
    glds16(gB1 + ko, &Bl[sl][tid * 8]);
    glds16(gB2 + ko, &Bl[sl][2048 + tid * 8]);
  };

  f32x4 acc[4][4] = {};
  const int nk = K >> 5;

  STAGE(0, 0);
  for (int kt = 0; kt < nk; ++kt) {
    const int s = kt & 1;
    if (kt + 1 < nk) {
      STAGE(s ^ 1, kt + 1);
      asm volatile("s_waitcnt vmcnt(4)" ::: "memory");
    } else {
      asm volatile("s_waitcnt vmcnt(0)" ::: "memory");
    }
    __builtin_amdgcn_s_barrier();
    bf16x8 af[4], bfr[4];
#pragma unroll
    for (int m = 0; m < 4; ++m) af[m] = *(const bf16x8*)&Al[s][aoff[m]];
#pragma unroll
    for (int n = 0; n < 4; ++n) bfr[n] = *(const bf16x8*)&Bl[s][boff[n]];
    __builtin_amdgcn_s_setprio(1);
#pragma unroll
    for (int m = 0; m < 4; ++m)
#pragma unroll
      for (int n = 0; n < 4; ++n)
        acc[m][n] = mfma16(af[m], bfr[n], acc[m][n]);
    __builtin_amdgcn_s_setprio(0);
    __builtin_amdgcn_s_barrier();   // guard: all reads of slot s done before overwrite
  }

  if (EPI == 0) {
#pragma unroll
    for (int m = 0; m < 4; ++m) {
      int row = bm * 128 + wm * 64 + m * 16 + g * 4;
#pragma unroll
      for (int n = 0; n < 4; ++n) {
        int col = bn * 128 + wn * 64 + n * 16 + r16;
#pragma unroll
        for (int r = 0; r < 4; ++r)
          stc(&C[(size_t)(row + r) * N + col], acc[m][n][r]);
      }
    }
  } else {
    // fused QKV epilogue.  This wave's 64 cols = exactly one head (or V slice).
    const int colbase = bn * 128 + wn * 64;
    const float QSCALE = 0.18033688011112042f;   // 0.125 * log2(e)
    if (colbase < DMODEL + DKV) {
      const bool isq = colbase < DMODEL;
      const float* wp = isq ? qw : kw;
      const float qs = isq ? QSCALE : 1.0f;
      float w4[4];
#pragma unroll
      for (int n = 0; n < 4; ++n) w4[n] = wp[n * 16 + r16];
#pragma unroll
      for (int m = 0; m < 4; ++m) {
        const int rowm = bm * 128 + wm * 64 + m * 16 + g * 4;
        float ss[4];
#pragma unroll
        for (int r = 0; r < 4; ++r) {
          ss[r] = acc[m][0][r] * acc[m][0][r] + acc[m][1][r] * acc[m][1][r] +
                  acc[m][2][r] * acc[m][2][r] + acc[m][3][r] * acc[m][3][r];
#pragma unroll
          for (int mk = 1; mk < 16; mk <<= 1) ss[r] += __shfl_xor(ss[r], mk);
          ss[r] = rsqrtf(ss[r] * (1.0f / HD) + 1e-6f);
        }
#pragma unroll
        for (int r = 0; r < 4; ++r) {
          const int t = rowm + r;
          const int sidx = t & (SEQ - 1);
          const float inv_ = ss[r];
#pragma unroll
          for (int n = 0; n < 4; ++n) {
            const int d = n * 16 + r16;
            const float xn = acc[m][n][r] * inv_ * w4[n];
            const float xp = acc[m][n ^ 2][r] * inv_ * w4[n ^ 2];
            const float rot = (n < 2) ? -xp : xp;
            const float cv = cosT[sidx * HD + d], sv = sinT[sidx * HD + d];
            const float o = (xn * cv + rot * sv) * qs;
            if (isq) {
              const int hq = colbase >> 6;
              Qr[((size_t)t * HH + hq) * HD + d] = (__bf16)o;
            } else {
              const int kvh = (colbase - DMODEL) >> 6;
              Kr[((size_t)t * KVHN + kvh) * HD + d] = (__bf16)o;
            }
          }
        }
      }
    } else {
      // V: write directly TRANSPOSED into VT[b][c][s].  The 4 r-values are
      // 4 consecutive tokens -> one bf16x4 (8B) store; g-lanes extend each
      // channel to a 32B contiguous run.
      const int vc0 = colbase - (DMODEL + DKV);
#pragma unroll
      for (int m = 0; m < 4; ++m) {
        const int rowm = bm * 128 + wm * 64 + m * 16 + g * 4;
        const int bb2 = rowm >> 11;          // batch (SEQ = 2048)
        const int s0 = rowm & (SEQ - 1);     // 4-aligned, same batch for r=0..3
#pragma unroll
        for (int n = 0; n < 4; ++n) {
          const int c = vc0 + n * 16 + r16;
          bf16x4 pk;
#pragma unroll
          for (int r = 0; r < 4; ++r) pk[r] = (__bf16)acc[m][n][r];
          *(bf16x4*)&Vt[((size_t)bb2 * DKV + c) * SEQ + s0] = pk;
        }
      }
    }
  }
}

// ---------------- flash attention (causal, GQA) ----------------
// R6/R11-proven geometry (best measured): grid flat 512, block 512 (8 waves
// x 16 q-rows; 16 waves/CU at 2 blocks/CU).  EQUAL-WORK BLOCKS: sequential
// complementary pair {15-j, j} (j = f&7) of 128-row q-tiles -> 34
// kv-iterations for EVERY block (equal wall-iterations AND compute).
// SWAPPED QK^T: sacc = mfma(kf, qf) gives S^T; lane(g,r16) holds
// S[kv=ks*16+g*4+r][q=r16] -> P store is 4x ds_write_b64 into row-major
// P[q][kv]; PV b128 read unchanged.  kf/vf reads are at the data-volume
// floor for 16 rows/wave; all geometry variants (32 rows/wave, concurrent
// pairs, 3-deep vmcnt) measured worse or neutral (rounds 7-9, 13).

__global__ __launch_bounds__(512)
void k_attn(const __bf16* __restrict__ Q, const __bf16* __restrict__ Kg,
            const __bf16* __restrict__ VT, __bf16* __restrict__ O) {
  __shared__ alignas(16) __bf16 Kl[2][64 * 64];
  __shared__ alignas(16) __bf16 Vl[2][64 * 64];
  __shared__ alignas(16) __bf16 Pl[8][16 * 72];
  const int f = blockIdx.x;
  const int b = f >> 8;
  const int h = (f & 255) >> 3;
  const int j = f & 7;
  const int kvh = h >> 2;
  const int tid = threadIdx.x, wid = tid >> 6, lane = tid & 63;
  const int g = lane >> 4, r16 = lane & 15;
  __bf16* Pw = Pl[wid];

  const int rr = lane >> 3;                 // row within wave's 8-row slab
  const int cc = (lane & 7) ^ rr;           // swizzled source chunk

  auto STAGE = [&](int buf, int kb) {
    const int krow = kb * 64 + wid * 8 + rr;
    glds16(&Kg[((size_t)(b * SEQ + krow) * KVHN + kvh) * HD + cc * 8],
           &Kl[buf][wid * 512]);
    const int d = wid * 8 + rr;
    glds16(&VT[(size_t)(b * DKV + kvh * HD + d) * SEQ + (size_t)kb * 64 + cc * 8],
           &Vl[buf][wid * 512]);
  };

#pragma unroll 1
  for (int phase = 0; phase < 2; ++phase) {
    const int qt = phase ? j : 15 - j;      // heavy tile first
    const int q0 = qt * 128 + wid * 16;
    const int ntile = 2 * qt + 2;

    bf16x8 qf[2];
#pragma unroll
    for (int h2 = 0; h2 < 2; ++h2)
      qf[h2] = *(const bf16x8*)&Q[(((size_t)b * SEQ + q0 + r16) * HH + h) * HD + h2 * 32 + g * 8];

    f32x4 acc[4] = {};
    float l_q = 0.0f;   // per-lane partial denominator for q = q0 + r16

    STAGE(0, 0);
    asm volatile("s_waitcnt vmcnt(0)" ::: "memory");
    __syncthreads();

    for (int kb = 0; kb < ntile; ++kb) {
      const int cur = kb & 1;
      if (kb + 1 < ntile) STAGE(cur ^ 1, kb + 1);   // prefetch next tile
      const __bf16* Kb = Kl[cur];
      const __bf16* Vb = Vl[cur];
      if (kb * 64 <= q0 + 15) {                     // tile intersects rows
        bf16x8 kf[4][2];
#pragma unroll
        for (int ks = 0; ks < 4; ++ks)
#pragma unroll
          for (int h2 = 0; h2 < 2; ++h2) {
            const int p = r16 + ks * 16;
            const int ch = (g + 4 * h2) ^ (p & 7);
            kf[ks][h2] = *(const bf16x8*)&Kb[p * 64 + ch * 8];
          }
        const bool needmask = (kb * 64 + 63 > q0); // only diagonal tiles mask
        float svv[4][4];
        __builtin_amdgcn_s_setprio(1);
#pragma unroll
        for (int ks = 0; ks < 4; ++ks) {
          f32x4 sacc = {-12.f, -12.f, -12.f, -12.f};   // fixed max in C-init
          sacc = mfma16(kf[ks][0], qf[0], sacc);       // SWAPPED: S^T
          sacc = mfma16(kf[ks][1], qf[1], sacc);
#pragma unroll
          for (int r = 0; r < 4; ++r) svv[ks][r] = sacc[r];
        }
        __builtin_amdgcn_s_setprio(0);
        if (needmask) {
#pragma unroll
          for (int ks = 0; ks < 4; ++ks)
#pragma unroll
            for (int r = 0; r < 4; ++r) {
              int pg = kb * 64 + ks * 16 + g * 4 + r;  // kv (swapped)
              int qg = q0 + r16;                       // q  (swapped)
              if (pg > qg) svv[ks][r] = -1e30f;
            }
        }
        // exp2 + packed b64 store into P[q=r16][kv]: contiguous 4 per ks
#pragma unroll
        for (int ks = 0; ks < 4; ++ks) {
          bf16x4 pk;
#pragma unroll
          for (int r = 0; r < 4; ++r) {
            float p = fast_exp2(svv[ks][r]);
            l_q += p;
            pk[r] = (__bf16)p;
          }
          *(bf16x4*)&Pw[r16 * 72 + ks * 16 + g * 4] = pk;
        }
        bf16x8 pf0 = *(const bf16x8*)&Pw[r16 * 72 + g * 8];
        bf16x8 pf1 = *(const bf16x8*)&Pw[r16 * 72 + 32 + g * 8];
        __builtin_amdgcn_s_setprio(1);
#pragma unroll
        for (int nb = 0; nb < 4; ++nb) {
          const int d = r16 + nb * 16;
          const int ch0 = g ^ (d & 7), ch1 = (4 + g) ^ (d & 7);
          bf16x8 vf0 = *(const bf16x8*)&Vb[d * 64 + ch0 * 8];
          bf16x8 vf1 = *(const bf16x8*)&Vb[d * 64 + ch1 * 8];
          acc[nb] = mfma16(pf0, vf0, acc[nb]);
          acc[nb] = mfma16(pf1, vf1, acc[nb]);
        }
        __builtin_amdgcn_s_setprio(0);
      }
      asm volatile("s_waitcnt vmcnt(0)" ::: "memory");
      __syncthreads();
    }
    // epilogue: complete l over kv (sum the 4 g-groups), redistribute, store
    l_q += __shfl_xor(l_q, 16);
    l_q += __shfl_xor(l_q, 32);
    const float invq = 1.0f / l_q;
    float inv[4];
#pragma unroll
    for (int r = 0; r < 4; ++r) inv[r] = __shfl(invq, g * 4 + r);
#pragma unroll
    for (int nb = 0; nb < 4; ++nb)
#pragma unroll
      for (int r = 0; r < 4; ++r)
        O[(((size_t)b * SEQ + q0 + g * 4 + r) * HH + h) * HD + nb * 16 + r16] =
            (__bf16)(acc[nb][r] * inv[r]);
  }
}

// ---------------- launch ----------------

extern "C" void kernel_launch(void* const* d_in, const int* in_sizes, int n_in,
                              void* d_out, int out_size, void* d_ws, size_t ws_size,
                              hipStream_t stream) {
  const float* hidden = (const float*)d_in[0];
  const float* cosT   = (const float*)d_in[1];
  const float* sinT   = (const float*)d_in[2];
  const float* wq     = (const float*)d_in[3];
  const float* wk     = (const float*)d_in[4];
  const float* wv     = (const float*)d_in[5];
  const float* wo     = (const float*)d_in[6];
  const float* qw     = (const float*)d_in[7];
  const float* kw     = (const float*)d_in[8];
  float* out = (float*)d_out;
  char* ws = (char*)d_ws;

  // workspace layout (64 MB, lifetime-aliased):
  __bf16* Abf  = (__bf16*)(ws);                      // [0,16M) hidden bf16; later Ob
  __bf16* Ob   = Abf;
  __bf16* WT   = (__bf16*)(ws + (16u << 20));        // [16,28M) qkv weights^T
  __bf16* Qr   = (__bf16*)(ws + (28u << 20));        // [28,44M) Q roped (log2 domain)
  __bf16* Kr   = (__bf16*)(ws + (44u << 20));        // [44,48M) K roped
  __bf16* VT   = (__bf16*)(ws + (52u << 20));        // [52,56M) V transposed (direct)
  __bf16* WoT  = (__bf16*)(ws + (56u << 20));        // [56,64M)

  k_prep<<<18432, 256, 0, stream>>>(hidden, Abf, wq, wk, wv, wo, WT, WoT);

  k_gemm3<1, __bf16><<<768, 256, 0, stream>>>(Abf, WT, (__bf16*)nullptr,
      NTOK, NQKV, DMODEL, cosT, sinT, qw, kw, Qr, Kr, VT);

  k_attn<<<dim3(512), 512, 0, stream>>>(Qr, Kr, VT, Ob);

  k_gemm3<0, float><<<512, 256, 0, stream>>>(Ob, WoT, out,
      NTOK, DMODEL, DMODEL, nullptr, nullptr, nullptr, nullptr,
      nullptr, nullptr, nullptr);
}

// Round 16
// 177.048 us; speedup vs baseline: 1.1265x; 1.0527x over previous
//
#include <hip/hip_runtime.h>
#include <hip/hip_bf16.h>

#define HH 32
#define KVHN 8
#define HD 64
#define DMODEL 2048
#define SEQ 2048
#define BB 2
#define NTOK 4096     // BB*SEQ
#define DKV 512       // KVHN*HD
#define NQKV 3072     // DMODEL + 2*DKV

typedef __bf16 bf16x8 __attribute__((ext_vector_type(8)));
typedef __bf16 bf16x4 __attribute__((ext_vector_type(4)));
typedef float  f32x4  __attribute__((ext_vector_type(4)));

typedef const __attribute__((address_space(1))) void gvoid_t;
typedef __attribute__((address_space(3))) void lvoid_t;

__device__ inline void glds16(const void* g, void* l) {
  __builtin_amdgcn_global_load_lds((gvoid_t*)g, (lvoid_t*)l, 16, 0, 0);
}

__device__ inline f32x4 mfma16(bf16x8 a, bf16x8 b, f32x4 c) {
  return __builtin_amdgcn_mfma_f32_16x16x32_bf16(a, b, c, 0, 0, 0);
}

// 2^x via v_exp_f32 (glibc shadows __exp2f; this is the HW op directly)
__device__ inline float fast_exp2(float x) {
  float r;
  asm("v_exp_f32 %0, %1" : "=v"(r) : "v"(x));
  return r;
}

// ---------------- merged prep kernel ----------------
// One launch, 18432 blocks of 256 threads, blockIdx-range dispatch:
//   [0, 8192)      hidden f32 -> bf16 (elementwise, 4/thread)
//   [8192, 12288)  wq transpose  -> WT[0..2048)
//   [12288, 14336) wk/wv transpose -> WT[2048..3072)
//   [14336, 18432) wo transpose  -> WoT
// HBM-bound (~13 us for ~108 MB of traffic).

__global__ __launch_bounds__(256)
void k_prep(const float* __restrict__ hidden, __bf16* __restrict__ Abf,
            const float* __restrict__ wq, const float* __restrict__ wk,
            const float* __restrict__ wv, const float* __restrict__ wo,
            __bf16* __restrict__ WT, __bf16* __restrict__ WoT) {
  __shared__ float tile[32][33];
  const int id = blockIdx.x, tid = threadIdx.x;
  if (id < 8192) {
    int i = (id * 256 + tid) * 4;
    f32x4 v = *(const f32x4*)(hidden + i);
    bf16x4 o;
    o[0] = (__bf16)v[0]; o[1] = (__bf16)v[1];
    o[2] = (__bf16)v[2]; o[3] = (__bf16)v[3];
    *(bf16x4*)(Abf + i) = o;
    return;
  }
  const float* W; __bf16* T; int K, N, n0, k0;
  if (id < 12288) {           // wq
    int t = id - 8192; W = wq; T = WT; K = 2048; N = 2048;
    n0 = (t & 63) * 32; k0 = (t >> 6) * 32;
  } else if (id < 14336) {    // wk (z=0) / wv (z=1)
    int t = id - 12288; int z = t >> 10;
    W = z ? wv : wk; T = WT + (size_t)(2048 + z * 512) * 2048;
    K = 2048; N = 512;
    n0 = (t & 15) * 32; k0 = ((t >> 4) & 63) * 32;
  } else {                    // wo
    int t = id - 14336; W = wo; T = WoT; K = 2048; N = 2048;
    n0 = (t & 63) * 32; k0 = (t >> 6) * 32;
  }
  int tx = tid & 31, ty = tid >> 5;
#pragma unroll
  for (int i = 0; i < 32; i += 8)
    tile[ty + i][tx] = W[(size_t)(k0 + ty + i) * N + n0 + tx];
  __syncthreads();
#pragma unroll
  for (int i = 0; i < 32; i += 8)
    T[(size_t)(n0 + ty + i) * K + k0 + tx] = (__bf16)tile[tx][ty + i];
}

// ---------------- QKV GEMM (proven r11 config): BK=32, 128x128 ----------------
// 4 waves, 32KB LDS, 3 blocks/CU (768-block grid all-resident), counted
// vmcnt(4), row-pair XOR-8 LDS (0 bank conflicts), setprio MFMA.  Fused
// epilogue: per-head RMSNorm + RoPE (Q pre-scaled 0.125*log2(e)); V written
// directly transposed into VT[b][c][s].
// QKV stays at BK=32: at 64KB LDS its 768-block grid would run a 256-block
// 1-block/CU tail (round-14 failure mode, -25%).

__device__ inline void stc(float* p, float v)  { *p = v; }
__device__ inline void stc(__bf16* p, float v) { *p = (__bf16)v; }

template <int EPI, typename CT>
__global__ __launch_bounds__(256, 4)
void k_gemm3(const __bf16* __restrict__ A, const __bf16* __restrict__ BT,
             CT* __restrict__ C, int M, int N, int K,
             const float* __restrict__ cosT, const float* __restrict__ sinT,
             const float* __restrict__ qw, const float* __restrict__ kw,
             __bf16* __restrict__ Qr, __bf16* __restrict__ Kr,
             __bf16* __restrict__ Vt) {
  __shared__ alignas(16) __bf16 Al[2][128 * 32];
  __shared__ alignas(16) __bf16 Bl[2][128 * 32];
  const int tid = threadIdx.x;
  const int wid = tid >> 6, lane = tid & 63, g = lane >> 4, r16 = lane & 15;
  const int wm = wid >> 1, wn = wid & 1;
  const int nbm = M >> 7, nbn = N >> 7;
  const int nwg = nbm * nbn;
  int id = blockIdx.x;
  id = (id & 7) * (nwg >> 3) + (id >> 3);   // XCD swizzle (nwg % 8 == 0 here)
  const int bm = id % nbm, bn = id / nbm;

  // staging source: inverse of the row-pair XOR-8 swizzle
  const int pp = tid >> 3;                  // line index 0..31 (rows 0..63)
  const int c8 = (tid & 7) ^ (pp & 7);
  const int sr1 = 2 * pp + (c8 >> 2);       // 0..63
  const int sr2 = 64 + sr1;                 // 64..127
  const int c1 = (c8 & 3) * 8;
  const __bf16* gA1 = A + (size_t)(bm * 128 + sr1) * K + c1;
  const __bf16* gA2 = A + (size_t)(bm * 128 + sr2) * K + c1;
  const __bf16* gB1 = BT + (size_t)(bn * 128 + sr1) * K + c1;
  const __bf16* gB2 = BT + (size_t)(bn * 128 + sr2) * K + c1;

  // fragment read offsets (row-pair swizzle)
  int aoff[4], boff[4];
#pragma unroll
  for (int m = 0; m < 4; ++m) {
    int row = wm * 64 + m * 16 + r16;
    aoff[m] = (row >> 1) * 64 + (((((row & 1) << 2) | g) ^ ((row >> 1) & 7)) * 8);
  }
#pragma unroll
  for (int n = 0; n < 4; ++n) {
    int row = wn * 64 + n * 16 + r16;
    boff[n] = (row >> 1) * 64 + (((((row & 1) << 2) | g) ^ ((row >> 1) & 7)) * 8);
  }

  auto STAGE = [&](int sl, int kt) {
    const int ko = kt * 32;
    glds16(gA1 + ko, &Al[sl][tid * 8]);
    glds16(gA2 + ko, &Al[sl][2048 + tid * 8]);
    glds16(gB1 + ko, &Bl[sl][tid * 8]);
    glds16(gB2 + ko, &Bl[sl][2048 + tid * 8]);
  };

  f32x4 acc[4][4] = {};
  const int nk = K >> 5;

  STAGE(0, 0);
  for (int kt = 0; kt < nk; ++kt) {
    const int s = kt & 1;
    if (kt + 1 < nk) {
      STAGE(s ^ 1, kt + 1);
      asm volatile("s_waitcnt vmcnt(4)" ::: "memory");
    } else {
      asm volatile("s_waitcnt vmcnt(0)" ::: "memory");
    }
    __builtin_amdgcn_s_barrier();
    bf16x8 af[4], bfr[4];
#pragma unroll
    for (int m = 0; m < 4; ++m) af[m] = *(const bf16x8*)&Al[s][aoff[m]];
#pragma unroll
    for (int n = 0; n < 4; ++n) bfr[n] = *(const bf16x8*)&Bl[s][boff[n]];
    __builtin_amdgcn_s_setprio(1);
#pragma unroll
    for (int m = 0; m < 4; ++m)
#pragma unroll
      for (int n = 0; n < 4; ++n)
        acc[m][n] = mfma16(af[m], bfr[n], acc[m][n]);
    __builtin_amdgcn_s_setprio(0);
    __builtin_amdgcn_s_barrier();   // guard: all reads of slot s done before overwrite
  }

  if (EPI == 0) {
#pragma unroll
    for (int m = 0; m < 4; ++m) {
      int row = bm * 128 + wm * 64 + m * 16 + g * 4;
#pragma unroll
      for (int n = 0; n < 4; ++n) {
        int col = bn * 128 + wn * 64 + n * 16 + r16;
#pragma unroll
        for (int r = 0; r < 4; ++r)
          stc(&C[(size_t)(row + r) * N + col], acc[m][n][r]);
      }
    }
  } else {
    // fused QKV epilogue.  This wave's 64 cols = exactly one head (or V slice).
    const int colbase = bn * 128 + wn * 64;
    const float QSCALE = 0.18033688011112042f;   // 0.125 * log2(e)
    if (colbase < DMODEL + DKV) {
      const bool isq = colbase < DMODEL;
      const float* wp = isq ? qw : kw;
      const float qs = isq ? QSCALE : 1.0f;
      float w4[4];
#pragma unroll
      for (int n = 0; n < 4; ++n) w4[n] = wp[n * 16 + r16];
#pragma unroll
      for (int m = 0; m < 4; ++m) {
        const int rowm = bm * 128 + wm * 64 + m * 16 + g * 4;
        float ss[4];
#pragma unroll
        for (int r = 0; r < 4; ++r) {
          ss[r] = acc[m][0][r] * acc[m][0][r] + acc[m][1][r] * acc[m][1][r] +
                  acc[m][2][r] * acc[m][2][r] + acc[m][3][r] * acc[m][3][r];
#pragma unroll
          for (int mk = 1; mk < 16; mk <<= 1) ss[r] += __shfl_xor(ss[r], mk);
          ss[r] = rsqrtf(ss[r] * (1.0f / HD) + 1e-6f);
        }
#pragma unroll
        for (int r = 0; r < 4; ++r) {
          const int t = rowm + r;
          const int sidx = t & (SEQ - 1);
          const float inv_ = ss[r];
#pragma unroll
          for (int n = 0; n < 4; ++n) {
            const int d = n * 16 + r16;
            const float xn = acc[m][n][r] * inv_ * w4[n];
            const float xp = acc[m][n ^ 2][r] * inv_ * w4[n ^ 2];
            const float rot = (n < 2) ? -xp : xp;
            const float cv = cosT[sidx * HD + d], sv = sinT[sidx * HD + d];
            const float o = (xn * cv + rot * sv) * qs;
            if (isq) {
              const int hq = colbase >> 6;
              Qr[((size_t)t * HH + hq) * HD + d] = (__bf16)o;
            } else {
              const int kvh = (colbase - DMODEL) >> 6;
              Kr[((size_t)t * KVHN + kvh) * HD + d] = (__bf16)o;
            }
          }
        }
      }
    } else {
      // V: write directly TRANSPOSED into VT[b][c][s].
      const int vc0 = colbase - (DMODEL + DKV);
#pragma unroll
      for (int m = 0; m < 4; ++m) {
        const int rowm = bm * 128 + wm * 64 + m * 16 + g * 4;
        const int bb2 = rowm >> 11;          // batch (SEQ = 2048)
        const int s0 = rowm & (SEQ - 1);
#pragma unroll
        for (int n = 0; n < 4; ++n) {
          const int c = vc0 + n * 16 + r16;
          bf16x4 pk;
#pragma unroll
          for (int r = 0; r < 4; ++r) pk[r] = (__bf16)acc[m][n][r];
          *(bf16x4*)&Vt[((size_t)bb2 * DKV + c) * SEQ + s0] = pk;
        }
      }
    }
  }
}

// ---------------- WO GEMM: BK=64, 128x128, 2-phase ----------------
// Rationale (round-13 counters): per-CU block-iter rate is identical at 2
// and 3 blocks/CU -> residency 2 saturates.  BK=64 HALVES the number of
// vmcnt/barrier drain events (64 -> 32 per block) at zero residency cost:
// WO's grid is 512 blocks = exactly 2/CU at 64KB LDS, ALL co-resident, no
// tail (the round-14 failure mode doesn't apply).  LDS layout: a 64-bf16
// row = one 128B line of 8 chunks, slot = chunk ^ (row&7) (the measured
// 0-conflict XOR-8 pattern).  Staging: linear dest, 8 glds/thread/tile,
// counted vmcnt(8).  Fragment (row, kk): offset row*64 +
// ((((kk<<2)|g) ^ (row&7))*8.

__global__ __launch_bounds__(256, 2)
void k_gemmW(const __bf16* __restrict__ A, const __bf16* __restrict__ BT,
             float* __restrict__ C, int M, int N, int K) {
  __shared__ alignas(16) __bf16 Al[2][128 * 64];
  __shared__ alignas(16) __bf16 Bl[2][128 * 64];
  const int tid = threadIdx.x;
  const int wid = tid >> 6, lane = tid & 63, g = lane >> 4, r16 = lane & 15;
  const int wm = wid >> 1, wn = wid & 1;
  const int nbm = M >> 7, nbn = N >> 7;
  const int nwg = nbm * nbn;
  int id = blockIdx.x;
  id = (id & 7) * (nwg >> 3) + (id >> 3);   // XCD swizzle (nwg % 8 == 0)
  const int bm = id % nbm, bn = id / nbm;

  // staging: dest chunk c = tid + 256k (k=0..3) -> row = (tid>>3)+32k,
  // slot = tid&7.  Source col = ((tid&7) ^ (row&7))*8; (32k)&7 == 0 so
  // row&7 == (tid>>3)&7 for all k -> col constant per thread.
  const int srow = tid >> 3;                // 0..31
  const int scol = ((tid & 7) ^ (srow & 7)) * 8;
  const __bf16* gA = A + (size_t)(bm * 128 + srow) * K + scol;
  const __bf16* gB = BT + (size_t)(bn * 128 + srow) * K + scol;

  auto STAGE = [&](int sl, int kt) {        // 8 glds / thread
    const int ko = kt * 64;
#pragma unroll
    for (int k = 0; k < 4; ++k) {
      glds16(gA + (size_t)(32 * k) * K + ko, &Al[sl][(tid + 256 * k) * 8]);
      glds16(gB + (size_t)(32 * k) * K + ko, &Bl[sl][(tid + 256 * k) * 8]);
    }
  };

  // fragment read offsets: (row, kk) -> row*64 + ((((kk<<2)|g)^(row&7))*8
  int aoff[4][2], boff[4][2];
#pragma unroll
  for (int m = 0; m < 4; ++m) {
    int row = wm * 64 + m * 16 + r16;
#pragma unroll
    for (int kk = 0; kk < 2; ++kk)
      aoff[m][kk] = row * 64 + ((((kk << 2) | g) ^ (row & 7)) * 8);
  }
#pragma unroll
  for (int n = 0; n < 4; ++n) {
    int row = wn * 64 + n * 16 + r16;
#pragma unroll
    for (int kk = 0; kk < 2; ++kk)
      boff[n][kk] = row * 64 + ((((kk << 2) | g) ^ (row & 7)) * 8);
  }

  f32x4 acc[4][4] = {};
  const int nk = K >> 6;                    // 32 iterations

  STAGE(0, 0);
  for (int kt = 0; kt < nk; ++kt) {
    const int s = kt & 1;
    if (kt + 1 < nk) {
      STAGE(s ^ 1, kt + 1);
      asm volatile("s_waitcnt vmcnt(8)" ::: "memory");
    } else {
      asm volatile("s_waitcnt vmcnt(0)" ::: "memory");
    }
    __builtin_amdgcn_s_barrier();
#pragma unroll
    for (int kk = 0; kk < 2; ++kk) {
      bf16x8 af[4], bfr[4];
#pragma unroll
      for (int m = 0; m < 4; ++m) af[m] = *(const bf16x8*)&Al[s][aoff[m][kk]];
#pragma unroll
      for (int n = 0; n < 4; ++n) bfr[n] = *(const bf16x8*)&Bl[s][boff[n][kk]];
      __builtin_amdgcn_s_setprio(1);
#pragma unroll
      for (int m = 0; m < 4; ++m)
#pragma unroll
        for (int n = 0; n < 4; ++n)
          acc[m][n] = mfma16(af[m], bfr[n], acc[m][n]);
      __builtin_amdgcn_s_setprio(0);
    }
    __builtin_amdgcn_s_barrier();   // guard: all reads of slot s done before overwrite
  }

#pragma unroll
  for (int m = 0; m < 4; ++m) {
    int row = bm * 128 + wm * 64 + m * 16 + g * 4;
#pragma unroll
    for (int n = 0; n < 4; ++n) {
      int col = bn * 128 + wn * 64 + n * 16 + r16;
#pragma unroll
      for (int r = 0; r < 4; ++r)
        C[(size_t)(row + r) * N + col] = acc[m][n][r];
    }
  }
}

// ---------------- flash attention (causal, GQA) ----------------
// R6/R11-proven geometry (best measured): grid flat 512, block 512 (8 waves
// x 16 q-rows; 16 waves/CU at 2 blocks/CU).  EQUAL-WORK BLOCKS: sequential
// complementary pair {15-j, j} (j = f&7) of 128-row q-tiles -> 34
// kv-iterations for EVERY block.  SWAPPED QK^T: sacc = mfma(kf, qf) gives
// S^T; P store is 4x ds_write_b64 into row-major P[q][kv]; PV b128 read
// unchanged.  All geometry variants measured worse or neutral (r7-9, r13).

__global__ __launch_bounds__(512)
void k_attn(const __bf16* __restrict__ Q, const __bf16* __restrict__ Kg,
            const __bf16* __restrict__ VT, __bf16* __restrict__ O) {
  __shared__ alignas(16) __bf16 Kl[2][64 * 64];
  __shared__ alignas(16) __bf16 Vl[2][64 * 64];
  __shared__ alignas(16) __bf16 Pl[8][16 * 72];
  const int f = blockIdx.x;
  const int b = f >> 8;
  const int h = (f & 255) >> 3;
  const int j = f & 7;
  const int kvh = h >> 2;
  const int tid = threadIdx.x, wid = tid >> 6, lane = tid & 63;
  const int g = lane >> 4, r16 = lane & 15;
  __bf16* Pw = Pl[wid];

  const int rr = lane >> 3;                 // row within wave's 8-row slab
  const int cc = (lane & 7) ^ rr;           // swizzled source chunk

  auto STAGE = [&](int buf, int kb) {
    const int krow = kb * 64 + wid * 8 + rr;
    glds16(&Kg[((size_t)(b * SEQ + krow) * KVHN + kvh) * HD + cc * 8],
           &Kl[buf][wid * 512]);
    const int d = wid * 8 + rr;
    glds16(&VT[(size_t)(b * DKV + kvh * HD + d) * SEQ + (size_t)kb * 64 + cc * 8],
           &Vl[buf][wid * 512]);
  };

#pragma unroll 1
  for (int phase = 0; phase < 2; ++phase) {
    const int qt = phase ? j : 15 - j;      // heavy tile first
    const int q0 = qt * 128 + wid * 16;
    const int ntile = 2 * qt + 2;

    bf16x8 qf[2];
#pragma unroll
    for (int h2 = 0; h2 < 2; ++h2)
      qf[h2] = *(const bf16x8*)&Q[(((size_t)b * SEQ + q0 + r16) * HH + h) * HD + h2 * 32 + g * 8];

    f32x4 acc[4] = {};
    float l_q = 0.0f;   // per-lane partial denominator for q = q0 + r16

    STAGE(0, 0);
    asm volatile("s_waitcnt vmcnt(0)" ::: "memory");
    __syncthreads();

    for (int kb = 0; kb < ntile; ++kb) {
      const int cur = kb & 1;
      if (kb + 1 < ntile) STAGE(cur ^ 1, kb + 1);   // prefetch next tile
      const __bf16* Kb = Kl[cur];
      const __bf16* Vb = Vl[cur];
      if (kb * 64 <= q0 + 15) {                     // tile intersects rows
        bf16x8 kf[4][2];
#pragma unroll
        for (int ks = 0; ks < 4; ++ks)
#pragma unroll
          for (int h2 = 0; h2 < 2; ++h2) {
            const int p = r16 + ks * 16;
            const int ch = (g + 4 * h2) ^ (p & 7);
            kf[ks][h2] = *(const bf16x8*)&Kb[p * 64 + ch * 8];
          }
        const bool needmask = (kb * 64 + 63 > q0); // only diagonal tiles mask
        float svv[4][4];
        __builtin_amdgcn_s_setprio(1);
#pragma unroll
        for (int ks = 0; ks < 4; ++ks) {
          f32x4 sacc = {-12.f, -12.f, -12.f, -12.f};   // fixed max in C-init
          sacc = mfma16(kf[ks][0], qf[0], sacc);       // SWAPPED: S^T
          sacc = mfma16(kf[ks][1], qf[1], sacc);
#pragma unroll
          for (int r = 0; r < 4; ++r) svv[ks][r] = sacc[r];
        }
        __builtin_amdgcn_s_setprio(0);
        if (needmask) {
#pragma unroll
          for (int ks = 0; ks < 4; ++ks)
#pragma unroll
            for (int r = 0; r < 4; ++r) {
              int pg = kb * 64 + ks * 16 + g * 4 + r;  // kv (swapped)
              int qg = q0 + r16;                       // q  (swapped)
              if (pg > qg) svv[ks][r] = -1e30f;
            }
        }
        // exp2 + packed b64 store into P[q=r16][kv]: contiguous 4 per ks
#pragma unroll
        for (int ks = 0; ks < 4; ++ks) {
          bf16x4 pk;
#pragma unroll
          for (int r = 0; r < 4; ++r) {
            float p = fast_exp2(svv[ks][r]);
            l_q += p;
            pk[r] = (__bf16)p;
          }
          *(bf16x4*)&Pw[r16 * 72 + ks * 16 + g * 4] = pk;
        }
        bf16x8 pf0 = *(const bf16x8*)&Pw[r16 * 72 + g * 8];
        bf16x8 pf1 = *(const bf16x8*)&Pw[r16 * 72 + 32 + g * 8];
        __builtin_amdgcn_s_setprio(1);
#pragma unroll
        for (int nb = 0; nb < 4; ++nb) {
          const int d = r16 + nb * 16;
          const int ch0 = g ^ (d & 7), ch1 = (4 + g) ^ (d & 7);
          bf16x8 vf0 = *(const bf16x8*)&Vb[d * 64 + ch0 * 8];
          bf16x8 vf1 = *(const bf16x8*)&Vb[d * 64 + ch1 * 8];
          acc[nb] = mfma16(pf0, vf0, acc[nb]);
          acc[nb] = mfma16(pf1, vf1, acc[nb]);
        }
        __builtin_amdgcn_s_setprio(0);
      }
      asm volatile("s_waitcnt vmcnt(0)" ::: "memory");
      __syncthreads();
    }
    // epilogue: complete l over kv (sum the 4 g-groups), redistribute, store
    l_q += __shfl_xor(l_q, 16);
    l_q += __shfl_xor(l_q, 32);
    const float invq = 1.0f / l_q;
    float inv[4];
#pragma unroll
    for (int r = 0; r < 4; ++r) inv[r] = __shfl(invq, g * 4 + r);
#pragma unroll
    for (int nb = 0; nb < 4; ++nb)
#pragma unroll
      for (int r = 0; r < 4; ++r)
        O[(((size_t)b * SEQ + q0 + g * 4 + r) * HH + h) * HD + nb * 16 + r16] =
            (__bf16)(acc[nb][r] * inv[r]);
  }
}

// ---------------- launch ----------------

extern "C" void kernel_launch(void* const* d_in, const int* in_sizes, int n_in,
                              void* d_out, int out_size, void* d_ws, size_t ws_size,
                              hipStream_t stream) {
  const float* hidden = (const float*)d_in[0];
  const float* cosT   = (const float*)d_in[1];
  const float* sinT   = (const float*)d_in[2];
  const float* wq     = (const float*)d_in[3];
  const float* wk     = (const float*)d_in[4];
  const float* wv     = (const float*)d_in[5];
  const float* wo     = (const float*)d_in[6];
  const float* qw     = (const float*)d_in[7];
  const float* kw     = (const float*)d_in[8];
  float* out = (float*)d_out;
  char* ws = (char*)d_ws;

  // workspace layout (64 MB, lifetime-aliased):
  __bf16* Abf  = (__bf16*)(ws);                      // [0,16M) hidden bf16; later Ob
  __bf16* Ob   = Abf;
  __bf16* WT   = (__bf16*)(ws + (16u << 20));        // [16,28M) qkv weights^T
  __bf16* Qr   = (__bf16*)(ws + (28u << 20));        // [28,44M) Q roped (log2 domain)
  __bf16* Kr   = (__bf16*)(ws + (44u << 20));        // [44,48M) K roped
  __bf16* VT   = (__bf16*)(ws + (52u << 20));        // [52,56M) V transposed (direct)
  __bf16* WoT  = (__bf16*)(ws + (56u << 20));        // [56,64M)

  k_prep<<<18432, 256, 0, stream>>>(hidden, Abf, wq, wk, wv, wo, WT, WoT);

  k_gemm3<1, __bf16><<<768, 256, 0, stream>>>(Abf, WT, (__bf16*)nullptr,
      NTOK, NQKV, DMODEL, cosT, sinT, qw, kw, Qr, Kr, VT);

  k_attn<<<dim3(512), 512, 0, stream>>>(Qr, Kr, VT, Ob);

  // WO: BK=64, 512 blocks = exactly 2/CU, all co-resident
  k_gemmW<<<512, 256, 0, stream>>>(Ob, WoT, out, NTOK, DMODEL, DMODEL);
}